// Round 12
// baseline (44.757 us; speedup 1.0000x reference)
//
#include <hip/hip_runtime.h>

#define NB 64
#define NT 48
#define NF 128
#define NE 64
#define NCD 32

#define LOG2E 1.4426950408889634f

typedef __attribute__((ext_vector_type(8))) short bf16x8;
typedef __attribute__((ext_vector_type(4))) float f32x4;
typedef __attribute__((ext_vector_type(2))) uint u32x2;

// ---- ws layout (bytes) ----
#define WS_MFLAG 0        // 8192 u32
#define WS_DB    32768    // 8192 u16: bf16(e0-e1)
#define WS_E1B   49152    // bf16(e1)
#define WS_EMB   65536    // bf16(emiss)
#define WS_WLB   81920    // bf16(attn_w * log2e)
#define WS_WT    98304    // [32][128] u16 compress_w^T (upper 64 k-rows E-permuted)
#define WS_BL    106496   // 128 f32 bias*log2e

__device__ __forceinline__ ushort f2bf(float x) {
    union { float f; uint u; } v; v.f = x;
    uint r = v.u + 0x7fffu + ((v.u >> 16) & 1u);   // RNE
    return (ushort)(r >> 16);
}
__device__ __forceinline__ uint pk_bf16(float lo, float hi) {   // v_cvt_pk_bf16_f32
    uint r; asm("v_cvt_pk_bf16_f32 %0, %1, %2" : "=v"(r) : "v"(lo), "v"(hi)); return r;
}
__device__ __forceinline__ float bflo(uint u) { union { uint u; float f; } v; v.u = u << 16; return v.f; }
__device__ __forceinline__ float bfhi(uint u) { union { uint u; float f; } v; v.u = u & 0xffff0000u; return v.f; }

#define TRR(dst, addr, IMM) \
    asm volatile("ds_read_b64_tr_b16 %0, %1 offset:" IMM : "=v"(dst) : "v"(addr))
#define PLSWAP(a, b) asm("v_permlane32_swap_b32 %0, %1" : "+v"(a), "+v"(b))

#define AGG_ISSUE(CR, TB, O0, O1, O2, O3, O4, O5, O6, O7) \
    TRR(CR[0], TB, O0); TRR(CR[1], TB, O1); \
    TRR(CR[2], TB, O2); TRR(CR[3], TB, O3); \
    TRR(CR[4], TB, O4); TRR(CR[5], TB, O5); \
    TRR(CR[6], TB, O6); TRR(CR[7], TB, O7);

// one shared TRR batch feeds BOTH rowgroups: 8 MFMAs
#define AGG_CONSUME2(CR, PFA, PFB, AGA, AGB) { \
    union { u32x2 d[2]; bf16x8 v; } q0, q1, q2, q3; \
    q0.d[0] = CR[0]; q0.d[1] = CR[1]; q1.d[0] = CR[2]; q1.d[1] = CR[3]; \
    q2.d[0] = CR[4]; q2.d[1] = CR[5]; q3.d[0] = CR[6]; q3.d[1] = CR[7]; \
    AGA[0] = __builtin_amdgcn_mfma_f32_16x16x32_bf16(q0.v, PFA, AGA[0], 0, 0, 0); \
    AGB[0] = __builtin_amdgcn_mfma_f32_16x16x32_bf16(q0.v, PFB, AGB[0], 0, 0, 0); \
    AGA[1] = __builtin_amdgcn_mfma_f32_16x16x32_bf16(q1.v, PFA, AGA[1], 0, 0, 0); \
    AGB[1] = __builtin_amdgcn_mfma_f32_16x16x32_bf16(q1.v, PFB, AGB[1], 0, 0, 0); \
    AGA[2] = __builtin_amdgcn_mfma_f32_16x16x32_bf16(q2.v, PFA, AGA[2], 0, 0, 0); \
    AGB[2] = __builtin_amdgcn_mfma_f32_16x16x32_bf16(q2.v, PFB, AGB[2], 0, 0, 0); \
    AGA[3] = __builtin_amdgcn_mfma_f32_16x16x32_bf16(q3.v, PFA, AGA[3], 0, 0, 0); \
    AGB[3] = __builtin_amdgcn_mfma_f32_16x16x32_bf16(q3.v, PFB, AGB[3], 0, 0, 0); }

#define PF_BUILD(PF, PP, KS) { \
    uint X0 = PP[4*(KS)], X1 = PP[4*(KS)+1], X2 = PP[4*(KS)+2], X3 = PP[4*(KS)+3]; \
    PLSWAP(X0, X2); PLSWAP(X1, X3); \
    PF.u[0] = X0; PF.u[1] = X1; PF.u[2] = X2; PF.u[3] = X3; }

#define LGKM_WAIT(N) \
    asm volatile("s_waitcnt lgkmcnt(" #N ")" ::: "memory"); \
    __builtin_amdgcn_sched_barrier(0);

// ---------------- kernel 1: prep ----------------
__global__ __launch_bounds__(256) void prep_kernel(
    const int* __restrict__ mask, const float* __restrict__ e0, const float* __restrict__ e1,
    const float* __restrict__ em, const float* __restrict__ aw, const float* __restrict__ ab,
    const float* __restrict__ cw,
    uint* __restrict__ mflag, ushort* __restrict__ db, ushort* __restrict__ e1b,
    ushort* __restrict__ emb, ushort* __restrict__ wlb, ushort* __restrict__ wt,
    float* __restrict__ bl)
{
    const int blk = blockIdx.x, tid = threadIdx.x;
    if (blk < 32) {                     // tables -> bf16 (+ D = e0-e1, w*log2e)
        int idx = blk * 256 + tid;      // 8192
        float e1v = e1[idx];
        e1b[idx] = f2bf(e1v);
        emb[idx] = f2bf(em[idx]);
        db[idx]  = f2bf(e0[idx] - e1v);
        wlb[idx] = f2bf(aw[idx] * LOG2E);
    } else if (blk < 64) {              // m[b,f] = any_t mask
        int idx = (blk - 32) * 256 + tid;
        int b = idx >> 7, f = idx & 127;
        const int* p = mask + b * (NT * NF) + f;
        int s = 0;
#pragma unroll
        for (int t = 0; t < NT; ++t) s += p[t * NF];
        mflag[idx] = (s != 0) ? 1u : 0u;
    } else if (blk < 80) {              // compress_w -> wt bf16 [32][128], upper half E-permuted
        int idx = (blk - 64) * 256 + tid;
        int k = idx >> 5, d = idx & 31;
        int kd;
        if (k < 64) kd = k;
        else {
            int kk = k - 64;            // E: swap bits 2 and 3 within each 32-group
            kd = 64 + ((kk & 51) | ((kk & 4) << 1) | ((kk & 8) >> 1));
        }
        wt[d * 128 + kd] = f2bf(cw[idx]);
    } else {                            // bias * log2e
        if (tid < NF) bl[tid] = ab[tid] * LOG2E;
    }
}

// ---------------- kernel 2: 4-wave x 32-row single-(b,t) pipeline ----------------
// Every shared-C LDS read (S A-frags, AGG TRR batch) feeds TWO 16-row groups ->
// per-bt LDS traffic ~halves vs 8-wave. Single chain keeps register peak ~130
// unified (fits the (256,3) ~170 budget; R10's dual-chain version spilled at 128).
// LDS: sC[9248] u16 = 18496 B. 3 blocks/CU, 12 waves/CU.
__global__ __launch_bounds__(256, 3) void fused_kernel(
    const float* __restrict__ input_x, const uint* __restrict__ mflag,
    const ushort* __restrict__ db, const ushort* __restrict__ e1b, const ushort* __restrict__ emb,
    const ushort* __restrict__ wlb, const float* __restrict__ blog,
    const ushort* __restrict__ wt, float* __restrict__ out)
{
    __shared__ ushort sC[9248];

    const int tid = threadIdx.x;
    const int bt = blockIdx.x;          // b*NT + t
    const int b = bt / NT;

    const int wv = tid >> 6, ln = tid & 63;
    const int lr = ln & 15, lg = ln >> 4;
    const int irow0 = wv * 32 + lr;     // rowgroup 0; rowgroup 1 = +16

    // per-lane base into sC (u16 units)
    const int abase = (lg >> 1) * 2312 + (lr >> 2) * 72 + (lr & 3) * 16 + (lg & 1) * 8;

    const float bl0 = blog[irow0];
    const float bl1 = blog[irow0 + 16];

    // ---- phase 1: c for both rowgroups; CW-frags in regs; C to LDS ----
    bf16x8 cwf[2][2];                   // [g][ks]
#pragma unroll
    for (int g = 0; g < 2; ++g) {
        const int irow = irow0 + g * 16;
        const float x = input_x[bt * NF + irow];
        const ushort* Mrow = (mflag[b * NF + irow] ? e1b : emb) + irow * NE;
        const ushort* Drow = db + irow * NE;
        const ushort* Wrow = wlb + irow * NE;
#pragma unroll
        for (int ks = 0; ks < 2; ++ks) {
            const int eo = ks * 32 + lg * 8;
            uint d4[4], m4[4], w4[4];
            *(uint4*)d4 = *(const uint4*)(Drow + eo);
            *(uint4*)m4 = *(const uint4*)(Mrow + eo);
            *(uint4*)w4 = *(const uint4*)(Wrow + eo);
            uint cb[4]; union { uint u[4]; bf16x8 v; } cu;
#pragma unroll
            for (int j = 0; j < 4; ++j) {
                float clo = fmaf(x, bflo(d4[j]), bflo(m4[j]));
                float chi = fmaf(x, bfhi(d4[j]), bfhi(m4[j]));
                cb[j] = pk_bf16(clo, chi);
                cu.u[j] = pk_bf16(clo * bflo(w4[j]), chi * bfhi(w4[j]));
            }
            cwf[g][ks] = cu.v;
            *(uint4*)&sC[abase + (wv * 2 + g) * 288 + ks * 4624] = *(uint4*)cb;
        }
    }
    __syncthreads();                    // the ONLY barrier

    // ---- S + SM per rowgroup (st[8] reused; A-frag reads shared conceptually) ----
    uint pp0[16], pp1[16];
    float inv0, inv1;
    {
        f32x4 st[8];
#pragma unroll
        for (int g = 0; g < 2; ++g) {
            const float blv = g ? bl1 : bl0;
            uint* pp = g ? pp1 : pp0;
#pragma unroll
            for (int jt = 0; jt < 8; ++jt) {
                f32x4 a = (f32x4){blv, blv, blv, blv};
                bf16x8 a0 = *(bf16x8*)&sC[abase + jt * 288];
                a = __builtin_amdgcn_mfma_f32_16x16x32_bf16(a0, cwf[g][0], a, 0, 0, 0);
                bf16x8 a1 = *(bf16x8*)&sC[abase + jt * 288 + 4624];
                a = __builtin_amdgcn_mfma_f32_16x16x32_bf16(a1, cwf[g][1], a, 0, 0, 0);
                st[jt] = a;
            }
            const int dt_ = wv * 2 + g;     // diagonal tile for this rowgroup
            float rs0 = 0.f, rs1 = 0.f, rs2 = 0.f, rs3 = 0.f;
#pragma unroll
            for (int jt = 0; jt < 8; ++jt) {
                f32x4 v = st[jt];
                float e0 = exp2f(v[0]);
                float e1 = exp2f(v[1]);
                float e2 = exp2f(v[2]);
                float e3 = exp2f(v[3]);
                if (jt == dt_) {            // wave-uniform branch
                    const bool on = (lg == (lr >> 2));
                    e0 = (on && (lr & 3) == 0) ? 0.f : e0;
                    e1 = (on && (lr & 3) == 1) ? 0.f : e1;
                    e2 = (on && (lr & 3) == 2) ? 0.f : e2;
                    e3 = (on && (lr & 3) == 3) ? 0.f : e3;
                }
                rs0 += e0; rs1 += e1; rs2 += e2; rs3 += e3;
                pp[2 * jt]     = pk_bf16(e0, e1);
                pp[2 * jt + 1] = pk_bf16(e2, e3);
            }
            float rs = (rs0 + rs1) + (rs2 + rs3);
            rs += __shfl_xor(rs, 16);
            rs += __shfl_xor(rs, 32);
            if (g) inv1 = 1.0f / (rs + 1e-8f); else inv0 = 1.0f / (rs + 1e-8f);
        }
    }

    // ---- AGG^T: shared TRR batches (2-deep pipeline), 8 MFMA per batch ----
    f32x4 agA[4], agB[4];
#pragma unroll
    for (int et = 0; et < 4; ++et) { agA[et] = (f32x4){0.f,0.f,0.f,0.f}; agB[et] = (f32x4){0.f,0.f,0.f,0.f}; }
    {
        const uint tb = (uint)(uintptr_t)&sC[0]
                      + 2u * (uint)(72 * (((lg >> 1) << 2) + (lg & 1)) + lr);
        u32x2 cA[8], cB[8];
        union { uint u[4]; bf16x8 v; } pfA0, pfB0, pfA1, pfB1, pfA2, pfB2, pfA3, pfB3;
        PF_BUILD(pfA0, pp0, 0); PF_BUILD(pfB0, pp1, 0);
        AGG_ISSUE(cA, tb, "0", "144", "4624", "4768", "9248", "9392", "13872", "14016");
        PF_BUILD(pfA1, pp0, 1); PF_BUILD(pfB1, pp1, 1);
        AGG_ISSUE(cB, tb, "1152", "1296", "5776", "5920", "10400", "10544", "15024", "15168");
        LGKM_WAIT(8);                   // batch 0 done (pure-DS, in-order)
        AGG_CONSUME2(cA, pfA0.v, pfB0.v, agA, agB);
        PF_BUILD(pfA2, pp0, 2); PF_BUILD(pfB2, pp1, 2);
        AGG_ISSUE(cA, tb, "2304", "2448", "6928", "7072", "11552", "11696", "16176", "16320");
        LGKM_WAIT(8);                   // batch 1 done
        AGG_CONSUME2(cB, pfA1.v, pfB1.v, agA, agB);
        PF_BUILD(pfA3, pp0, 3); PF_BUILD(pfB3, pp1, 3);
        AGG_ISSUE(cB, tb, "3456", "3600", "8080", "8224", "12704", "12848", "17328", "17472");
        LGKM_WAIT(8);                   // batch 2 done
        AGG_CONSUME2(cA, pfA2.v, pfB2.v, agA, agB);
        LGKM_WAIT(0);                   // batch 3 done
        AGG_CONSUME2(cB, pfA3.v, pfB3.v, agA, agB);
    }

    // ---- Wt B-frag prefetch (pp dead -> register room) ----
    bf16x8 wf[8];
#pragma unroll
    for (int ks = 0; ks < 4; ++ks)
#pragma unroll
        for (int dt = 0; dt < 2; ++dt)
            wf[ks * 2 + dt] = *(const bf16x8*)(wt + (dt * 16 + lr) * 128 + ks * 32 + lg * 8);

    // ---- EPI per rowgroup: normalize, .*C, relu -> packed aa ----
    uint aa0[8], aa1[8];
#pragma unroll
    for (int g = 0; g < 2; ++g) {
        const f32x4* ag = g ? agB : agA;
        const float inv = g ? inv1 : inv0;
        uint* aa = g ? aa1 : aa0;
        const int ebase = (wv * 8 + g * 4 + (lr >> 2)) * 72 + (lr & 3) * 16 + lg * 4;
#pragma unroll
        for (int et = 0; et < 4; ++et) {
            u32x2 cb2 = *(u32x2*)&sC[ebase + et * 2312];
            float a0f = fmaxf(ag[et][0] * inv * bflo(cb2.x), 0.f);
            float a1f = fmaxf(ag[et][1] * inv * bfhi(cb2.x), 0.f);
            float a2f = fmaxf(ag[et][2] * inv * bflo(cb2.y), 0.f);
            float a3f = fmaxf(ag[et][3] * inv * bfhi(cb2.y), 0.f);
            aa[2 * et]     = pk_bf16(a0f, a1f);
            aa[2 * et + 1] = pk_bf16(a2f, a3f);
        }
    }

    // ---- OUT per rowgroup: relu([C, A2]) @ Wc ----
    float* op = out + bt * (NF * NCD);
#pragma unroll
    for (int g = 0; g < 2; ++g) {
        uint* aa = g ? aa1 : aa0;
        f32x4 oc[2];
        oc[0] = (f32x4){0.f, 0.f, 0.f, 0.f};
        oc[1] = (f32x4){0.f, 0.f, 0.f, 0.f};
#pragma unroll
        for (int ks = 0; ks < 4; ++ks) {
            bf16x8 afr;
            if (ks < 2) {
                const uint4 cc = *(uint4*)&sC[abase + (wv * 2 + g) * 288 + ks * 4624];
                union { uint u[4]; bf16x8 v; } rl;
                asm("v_pk_max_i16 %0, %1, 0" : "=v"(rl.u[0]) : "v"(cc.x));
                asm("v_pk_max_i16 %0, %1, 0" : "=v"(rl.u[1]) : "v"(cc.y));
                asm("v_pk_max_i16 %0, %1, 0" : "=v"(rl.u[2]) : "v"(cc.z));
                asm("v_pk_max_i16 %0, %1, 0" : "=v"(rl.u[3]) : "v"(cc.w));
                afr = rl.v;
            } else {
                const int kk = ks - 2;
                uint Y0 = aa[4 * kk], Y1 = aa[4 * kk + 1], Y2 = aa[4 * kk + 2], Y3 = aa[4 * kk + 3];
                PLSWAP(Y0, Y2);
                PLSWAP(Y1, Y3);
                union { uint u[4]; bf16x8 v; } af;
                af.u[0] = Y0; af.u[1] = Y1; af.u[2] = Y2; af.u[3] = Y3;
                afr = af.v;
            }
            oc[0] = __builtin_amdgcn_mfma_f32_16x16x32_bf16(afr, wf[ks * 2 + 0], oc[0], 0, 0, 0);
            oc[1] = __builtin_amdgcn_mfma_f32_16x16x32_bf16(afr, wf[ks * 2 + 1], oc[1], 0, 0, 0);
        }
#pragma unroll
        for (int dt = 0; dt < 2; ++dt)
#pragma unroll
            for (int r = 0; r < 4; ++r)
                op[(wv * 32 + g * 16 + lg * 4 + r) * NCD + dt * 16 + lr] = oc[dt][r];
    }
}

extern "C" void kernel_launch(void* const* d_in, const int* in_sizes, int n_in,
                              void* d_out, int out_size, void* d_ws, size_t ws_size,
                              hipStream_t stream) {
    const float* input_x       = (const float*)d_in[0];
    const int*   mask          = (const int*)d_in[1];
    const float* embed0        = (const float*)d_in[2];
    const float* embed1        = (const float*)d_in[3];
    const float* embed_missing = (const float*)d_in[4];
    const float* attn_w        = (const float*)d_in[5];
    const float* attn_b        = (const float*)d_in[6];
    const float* compress_w    = (const float*)d_in[7];
    float* out = (float*)d_out;

    char* ws = (char*)d_ws;
    uint*   mflag = (uint*)(ws + WS_MFLAG);
    ushort* dbp   = (ushort*)(ws + WS_DB);
    ushort* e1bp  = (ushort*)(ws + WS_E1B);
    ushort* embp  = (ushort*)(ws + WS_EMB);
    ushort* wlbp  = (ushort*)(ws + WS_WLB);
    ushort* wtp   = (ushort*)(ws + WS_WT);
    float*  blp   = (float*)(ws + WS_BL);

    hipLaunchKernelGGL(prep_kernel, dim3(81), dim3(256), 0, stream,
                       mask, embed0, embed1, embed_missing, attn_w, attn_b, compress_w,
                       mflag, dbp, e1bp, embp, wlbp, wtp, blp);
    hipLaunchKernelGGL(fused_kernel, dim3(NB * NT), dim3(256), 0, stream,
                       input_x, mflag, dbp, e1bp, embp, wlbp, blp, wtp, out);
}